// Round 11
// baseline (503.433 us; speedup 1.0000x reference)
//
#include <hip/hip_runtime.h>
#include <math.h>

#define N_NODES 50000
#define N_EDGES 800000
#define F_IN 64
#define D 128
#define NLAYER 3
#define B_GRAPHS 8
#define GB 32               // input_proj: nodes per block
#define NBLK ((N_NODES + GB - 1) / GB)            // 1563
#define WNODE 16            // v9: nodes per wave
#define GB2 64              // v9: nodes per block (4 waves x 16)
#define NBLK2 ((N_NODES + GB2 - 1) / GB2)         // 782
#define SCAN_B 512
#define NPART ((N_NODES + SCAN_B - 1) / SCAN_B)   // 98
#define AGP 136             // agg LDS row stride in ushorts

typedef float f32x4 __attribute__((ext_vector_type(4)));
typedef short bf16x8 __attribute__((ext_vector_type(8)));

__device__ __forceinline__ float gelu_exact(float x) {
    return 0.5f * x * (1.0f + erff(x * 0.7071067811865476f));
}

__device__ __forceinline__ unsigned short f2bf(float f) {
    unsigned int u = __float_as_uint(f);
    u = (u + 0x7fffu + ((u >> 16) & 1u)) >> 16;
    return (unsigned short)u;
}
__device__ __forceinline__ float bf2f(unsigned short u) {
    return __uint_as_float((unsigned int)u << 16);
}

// ---------------- CSR build ----------------

__global__ void degree_kernel(const int* __restrict__ dst, int* __restrict__ deg) {
    int e = blockIdx.x * blockDim.x + threadIdx.x;
    if (e < N_EDGES) atomicAdd(&deg[dst[e]], 1);
}

__global__ __launch_bounds__(SCAN_B) void scan_partials_kernel(const int* __restrict__ deg,
                                                               int* __restrict__ partials) {
    __shared__ int wsum[8];
    int tid = threadIdx.x;
    int lane = tid & 63, wave = tid >> 6;
    int i = blockIdx.x * SCAN_B + tid;
    int v = (i < N_NODES) ? deg[i] : 0;
    #pragma unroll
    for (int o = 32; o >= 1; o >>= 1) v += __shfl_xor(v, o);
    if (lane == 0) wsum[wave] = v;
    __syncthreads();
    if (tid == 0) {
        int t = 0;
        #pragma unroll
        for (int w = 0; w < 8; ++w) t += wsum[w];
        partials[blockIdx.x] = t;
    }
}

__global__ __launch_bounds__(SCAN_B) void scan_apply_v2(const int* __restrict__ deg,
        const int* __restrict__ partials, int* __restrict__ row_ptr, int* __restrict__ cursor) {
    __shared__ int wsum[8];
    __shared__ int base_s;
    int tid = threadIdx.x;
    int lane = tid & 63, wave = tid >> 6;

    int b = 0;
    for (int i = tid; i < (int)blockIdx.x; i += SCAN_B) b += partials[i];
    #pragma unroll
    for (int o = 32; o >= 1; o >>= 1) b += __shfl_xor(b, o);
    if (lane == 0) wsum[wave] = b;
    __syncthreads();
    if (tid == 0) {
        int t = 0;
        #pragma unroll
        for (int w = 0; w < 8; ++w) t += wsum[w];
        base_s = t;
    }
    __syncthreads();
    int base = base_s;
    __syncthreads();

    if (blockIdx.x == 0) {
        int t = 0;
        for (int i = tid; i < NPART; i += SCAN_B) t += partials[i];
        #pragma unroll
        for (int o = 32; o >= 1; o >>= 1) t += __shfl_xor(t, o);
        if (lane == 0) wsum[wave] = t;
        __syncthreads();
        if (tid == 0) {
            int tt = 0;
            #pragma unroll
            for (int w = 0; w < 8; ++w) tt += wsum[w];
            row_ptr[N_NODES] = tt;
        }
        __syncthreads();
    }

    int i = blockIdx.x * SCAN_B + tid;
    int v = (i < N_NODES) ? deg[i] : 0;
    int x = v;
    #pragma unroll
    for (int o = 1; o < 64; o <<= 1) { int nb = __shfl_up(x, o); if (lane >= o) x += nb; }
    if (lane == 63) wsum[wave] = x;
    __syncthreads();
    int waveoff = 0;
    #pragma unroll
    for (int w = 0; w < 8; ++w) waveoff += (w < wave) ? wsum[w] : 0;
    int excl = base + waveoff + x - v;
    if (i < N_NODES) { row_ptr[i] = excl; cursor[i] = excl; }
}

__global__ void fill_kernel(const int* __restrict__ src, const int* __restrict__ dst,
                            int* __restrict__ cursor, int* __restrict__ csr) {
    int e = blockIdx.x * blockDim.x + threadIdx.x;
    if (e < N_EDGES) {
        int t = dst[e];
        int pos = atomicAdd(&cursor[t], 1);
        csr[pos] = src[e];
    }
}

// W prep: gnn_w -> wt bf16 [L][n=D][k=2D]; gate_w1 -> [n=D][k=D]; w_in -> [n=D][k=F_IN]
#define WT_GNN (NLAYER * D * 2 * D)
#define WT_G1  (WT_GNN + D * D)
#define WT_ALL (WT_G1 + D * F_IN)
__global__ void wprep_kernel(const float* __restrict__ gnn_w, const float* __restrict__ gate_w1,
                             const float* __restrict__ w_in, unsigned short* __restrict__ wt,
                             float* __restrict__ pooled) {
    int idx = blockIdx.x * 256 + threadIdx.x;
    if (blockIdx.x == 0) {
        #pragma unroll
        for (int i = 0; i < 4; ++i) pooled[threadIdx.x + i * 256] = 0.f;
    }
    if (idx >= WT_ALL) return;
    if (idx < WT_GNN) {
        int l = idx / (D * 2 * D);
        int rem = idx - l * (D * 2 * D);
        int n = rem / (2 * D);
        int k = rem - n * (2 * D);
        wt[idx] = f2bf(gnn_w[(size_t)l * 2 * D * D + (size_t)k * D + n]);
    } else if (idx < WT_G1) {
        int rem = idx - WT_GNN;
        int n = rem / D;
        int k = rem - n * D;
        wt[idx] = f2bf(gate_w1[(size_t)k * D + n]);
    } else {
        int rem = idx - WT_G1;
        int n = rem / F_IN;
        int k = rem - n * F_IN;
        wt[idx] = f2bf(w_in[(size_t)k * D + n]);
    }
}

// ---------------- input proj v5: MFMA ----------------

__global__ __launch_bounds__(256) void input_proj_v5(
        const float* __restrict__ x, const unsigned short* __restrict__ wti,
        const float* __restrict__ b, const float* __restrict__ gam,
        const float* __restrict__ bet, unsigned short* __restrict__ h16) {
    __shared__ float2 red[2][GB];
    int tid = threadIdx.x;
    int wave = tid >> 6, lane = tid & 63;
    int nblk0 = blockIdx.x * GB;
    int q = lane >> 4, c = lane & 15;
    int m0 = (wave >> 1) * 16;
    int n0 = (wave & 1) * 64;
    int mrow = nblk0 + m0 + c;
    int mclamp = (mrow < N_NODES) ? mrow : (N_NODES - 1);
    const float* xr = x + (size_t)mclamp * F_IN;

    f32x4 acc[4];
    #pragma unroll
    for (int t = 0; t < 4; ++t) {
        float bn = b[n0 + t * 16 + c];
        acc[t] = (f32x4){bn, bn, bn, bn};
    }
    #pragma unroll
    for (int kk = 0; kk < 2; ++kk) {
        float4 a0 = *(const float4*)&xr[kk * 32 + q * 8];
        float4 a1 = *(const float4*)&xr[kk * 32 + q * 8 + 4];
        bf16x8 av;
        av[0] = (short)f2bf(a0.x); av[1] = (short)f2bf(a0.y);
        av[2] = (short)f2bf(a0.z); av[3] = (short)f2bf(a0.w);
        av[4] = (short)f2bf(a1.x); av[5] = (short)f2bf(a1.y);
        av[6] = (short)f2bf(a1.z); av[7] = (short)f2bf(a1.w);
        #pragma unroll
        for (int t = 0; t < 4; ++t) {
            bf16x8 bv = *(const bf16x8*)&wti[(size_t)(n0 + t * 16 + c) * F_IN + kk * 32 + q * 8];
            acc[t] = __builtin_amdgcn_mfma_f32_16x16x32_bf16(av, bv, acc[t], 0, 0, 0);
        }
    }
    float s[4], sq[4];
    #pragma unroll
    for (int r = 0; r < 4; ++r) {
        s[r] = acc[0][r] + acc[1][r] + acc[2][r] + acc[3][r];
        sq[r] = acc[0][r] * acc[0][r] + acc[1][r] * acc[1][r]
              + acc[2][r] * acc[2][r] + acc[3][r] * acc[3][r];
    }
    #pragma unroll
    for (int o = 1; o <= 8; o <<= 1)
        #pragma unroll
        for (int r = 0; r < 4; ++r) { s[r] += __shfl_xor(s[r], o); sq[r] += __shfl_xor(sq[r], o); }
    if (c == 0) {
        #pragma unroll
        for (int r = 0; r < 4; ++r) red[wave & 1][m0 + q * 4 + r] = make_float2(s[r], sq[r]);
    }
    __syncthreads();
    float gv[4], bv2[4];
    #pragma unroll
    for (int t = 0; t < 4; ++t) {
        int nn = n0 + t * 16 + c;
        gv[t] = gam[nn]; bv2[t] = bet[nn];
    }
    #pragma unroll
    for (int r = 0; r < 4; ++r) {
        int m = m0 + q * 4 + r;
        int n = nblk0 + m;
        float2 p0 = red[0][m], p1 = red[1][m];
        float mean = (p0.x + p1.x) * (1.0f / D);
        float msq  = (p0.y + p1.y) * (1.0f / D);
        float istd = rsqrtf(msq - mean * mean + 1e-5f);
        if (n < N_NODES) {
            #pragma unroll
            for (int t = 0; t < 4; ++t) {
                int nn = n0 + t * 16 + c;
                float y = (acc[t][r] - mean) * istd * gv[t] + bv2[t];
                h16[(size_t)n * D + nn] = f2bf(gelu_exact(y));
            }
        }
    }
}

// ---------------- GNN layer v9: wave-independent (no barriers), 16 nodes x 128 dims/wave --

__device__ __forceinline__ void acc_row(float acc[8], bf16x8 v) {
    #pragma unroll
    for (int i = 0; i < 8; ++i)
        acc[i] += __uint_as_float(((unsigned int)(unsigned short)v[i]) << 16);
}

template<int DO_GATE>
__global__ __launch_bounds__(256) void gnn_layer_v9(
        const unsigned short* __restrict__ h16_in, unsigned short* __restrict__ h16_out,
        float* __restrict__ hf_out,
        const int* __restrict__ csr, const int* __restrict__ rp,
        const unsigned short* __restrict__ wt,   // [n=D][k=2D] bf16
        const float* __restrict__ bias,
        const float* __restrict__ ln1g, const float* __restrict__ ln1b,
        const float* __restrict__ ln2g, const float* __restrict__ ln2b,
        int residual, int write_f32,
        const unsigned short* __restrict__ wtg,
        const float* __restrict__ gb1, const float* __restrict__ gw2,
        const float* __restrict__ gb2,
        float* __restrict__ logits, float2* __restrict__ gpart) {
    __shared__ int rps[4][WNODE + 1];
    __shared__ int eidx[4][WNODE][32];          // 8 KB
    __shared__ unsigned short aggb[4][WNODE][AGP];  // 17.4 KB (agg; reused for gate staging)
    __shared__ float lg[GB2];

    int tid = threadIdx.x;
    int wave = tid >> 6, lane = tid & 63;
    int nw0 = blockIdx.x * GB2 + wave * WNODE;  // wave's first node
    int er = lane >> 4, dg = lane & 15;

    // wave-private row_ptr slice
    if (lane < WNODE + 1) {
        int n = nw0 + lane;
        if (n > N_NODES) n = N_NODES;
        rps[wave][lane] = rp[n];
    }
    // wave-private edge-index fill: 2 nodes per iteration, coalesced
    #pragma unroll
    for (int it = 0; it < 8; ++it) {
        int j = it * 2 + (lane >> 5);
        int sl = lane & 31;
        int beg = rps[wave][j], end = rps[wave][j + 1];
        int ee = beg + sl;
        int ci = (ee < end) ? ee : ((end > beg) ? (end - 1) : 0);
        eidx[wave][j][sl] = csr[ci];
    }

    // gather: node pairs; 16 slots unconditional, +16 if deg>16 (wave-uniform)
    #pragma unroll
    for (int jj = 0; jj < WNODE; jj += 2) {
        int begA = rps[wave][jj], endA = rps[wave][jj + 1];
        int begB = endA, endB = rps[wave][jj + 2];
        int degA = endA - begA, degB = endB - begB;
        int idA[4], idB[4];
        #pragma unroll
        for (int t = 0; t < 4; ++t) {
            idA[t] = eidx[wave][jj][er + 4 * t];
            idB[t] = eidx[wave][jj + 1][er + 4 * t];
        }
        bf16x8 vA[4], vB[4];
        #pragma unroll
        for (int t = 0; t < 4; ++t)
            vA[t] = *(const bf16x8*)&h16_in[(size_t)idA[t] * D + dg * 8];
        #pragma unroll
        for (int t = 0; t < 4; ++t)
            vB[t] = *(const bf16x8*)&h16_in[(size_t)idB[t] * D + dg * 8];
        float accA[8], accB[8];
        #pragma unroll
        for (int i = 0; i < 8; ++i) { accA[i] = 0.f; accB[i] = 0.f; }
        #pragma unroll
        for (int t = 0; t < 4; ++t) {
            if (begA + er + 4 * t < endA) acc_row(accA, vA[t]);
            if (begB + er + 4 * t < endB) acc_row(accB, vB[t]);
        }
        if (degA > 16 || degB > 16) {
            int idA2[4], idB2[4];
            #pragma unroll
            for (int t = 0; t < 4; ++t) {
                idA2[t] = eidx[wave][jj][16 + er + 4 * t];
                idB2[t] = eidx[wave][jj + 1][16 + er + 4 * t];
            }
            bf16x8 wA[4], wB[4];
            #pragma unroll
            for (int t = 0; t < 4; ++t)
                wA[t] = *(const bf16x8*)&h16_in[(size_t)idA2[t] * D + dg * 8];
            #pragma unroll
            for (int t = 0; t < 4; ++t)
                wB[t] = *(const bf16x8*)&h16_in[(size_t)idB2[t] * D + dg * 8];
            #pragma unroll
            for (int t = 0; t < 4; ++t) {
                if (begA + 16 + er + 4 * t < endA) acc_row(accA, wA[t]);
                if (begB + 16 + er + 4 * t < endB) acc_row(accB, wB[t]);
            }
            if (degA > 32)
                for (int ee = begA + er + 32; ee < endA; ee += 4) {
                    bf16x8 vv = *(const bf16x8*)&h16_in[(size_t)csr[ee] * D + dg * 8];
                    acc_row(accA, vv);
                }
            if (degB > 32)
                for (int ee = begB + er + 32; ee < endB; ee += 4) {
                    bf16x8 vv = *(const bf16x8*)&h16_in[(size_t)csr[ee] * D + dg * 8];
                    acc_row(accB, vv);
                }
        }
        #pragma unroll
        for (int i = 0; i < 8; ++i) {
            accA[i] += __shfl_xor(accA[i], 16);
            accA[i] += __shfl_xor(accA[i], 32);
            accB[i] += __shfl_xor(accB[i], 16);
            accB[i] += __shfl_xor(accB[i], 32);
        }
        float invA = 1.0f / fmaxf((float)degA, 1.0f);
        float invB = 1.0f / fmaxf((float)degB, 1.0f);
        if (er == 0) {
            bf16x8 oA, oB;
            #pragma unroll
            for (int i = 0; i < 8; ++i) {
                oA[i] = (short)f2bf(accA[i] * invA);
                oB[i] = (short)f2bf(accB[i] * invB);
            }
            *(bf16x8*)&aggb[wave][jj][dg * 8] = oA;
            *(bf16x8*)&aggb[wave][jj + 1][dg * 8] = oB;
        }
    }
    // no barrier: LDS is wave-private, in-wave program order suffices

    // ---- MFMA GEMM: wave tile = 16 nodes x 128 dims; K=256
    int q = lane >> 4, c = lane & 15;
    int mrow = nw0 + c;
    int mclamp = (mrow < N_NODES) ? mrow : (N_NODES - 1);
    const unsigned short* arow = h16_in + (size_t)mclamp * D;

    f32x4 acc[8];
    #pragma unroll
    for (int t = 0; t < 8; ++t) {
        float bn = bias[t * 16 + c];
        acc[t] = (f32x4){bn, bn, bn, bn};
    }
    #pragma unroll
    for (int kk = 0; kk < 4; ++kk) {      // self half from global
        bf16x8 av = *(const bf16x8*)&arow[kk * 32 + q * 8];
        #pragma unroll
        for (int t = 0; t < 8; ++t) {
            bf16x8 bv = *(const bf16x8*)&wt[(size_t)(t * 16 + c) * 256 + kk * 32 + q * 8];
            acc[t] = __builtin_amdgcn_mfma_f32_16x16x32_bf16(av, bv, acc[t], 0, 0, 0);
        }
    }
    #pragma unroll
    for (int kk = 0; kk < 4; ++kk) {      // agg half from wave-private LDS
        bf16x8 av = *(const bf16x8*)&aggb[wave][c][kk * 32 + q * 8];
        #pragma unroll
        for (int t = 0; t < 8; ++t) {
            bf16x8 bv = *(const bf16x8*)&wt[(size_t)(t * 16 + c) * 256 + 128 + kk * 32 + q * 8];
            acc[t] = __builtin_amdgcn_mfma_f32_16x16x32_bf16(av, bv, acc[t], 0, 0, 0);
        }
    }

    // ---- epilogue (all in-wave): gelu -> LN1 -> LN2 -> (gelu+residual)
    float xv[8][4];
    #pragma unroll
    for (int t = 0; t < 8; ++t)
        #pragma unroll
        for (int r = 0; r < 4; ++r) xv[t][r] = gelu_exact(acc[t][r]);

    float s[4], sq[4];
    #pragma unroll
    for (int r = 0; r < 4; ++r) {
        s[r] = 0.f; sq[r] = 0.f;
        #pragma unroll
        for (int t = 0; t < 8; ++t) { s[r] += xv[t][r]; sq[r] += xv[t][r] * xv[t][r]; }
    }
    #pragma unroll
    for (int o = 1; o <= 8; o <<= 1)
        #pragma unroll
        for (int r = 0; r < 4; ++r) { s[r] += __shfl_xor(s[r], o); sq[r] += __shfl_xor(sq[r], o); }

    float g1v[8], b1v[8], g2v[8], b2v[8];
    #pragma unroll
    for (int t = 0; t < 8; ++t) {
        int nn = t * 16 + c;
        g1v[t] = ln1g[nn]; b1v[t] = ln1b[nn];
        g2v[t] = ln2g[nn]; b2v[t] = ln2b[nn];
    }

    float y1[8][4];
    float s2[4], sq2[4];
    #pragma unroll
    for (int r = 0; r < 4; ++r) {
        float mean = s[r] * (1.0f / D);
        float msq  = sq[r] * (1.0f / D);
        float istd = rsqrtf(msq - mean * mean + 1e-5f);
        s2[r] = 0.f; sq2[r] = 0.f;
        #pragma unroll
        for (int t = 0; t < 8; ++t) {
            float y = (xv[t][r] - mean) * istd * g1v[t] + b1v[t];
            y1[t][r] = y;
            s2[r] += y; sq2[r] += y * y;
        }
    }
    #pragma unroll
    for (int o = 1; o <= 8; o <<= 1)
        #pragma unroll
        for (int r = 0; r < 4; ++r) { s2[r] += __shfl_xor(s2[r], o); sq2[r] += __shfl_xor(sq2[r], o); }

    #pragma unroll
    for (int r = 0; r < 4; ++r) {
        int m = q * 4 + r;
        int n = nw0 + m;
        float mean = s2[r] * (1.0f / D);
        float msq  = sq2[r] * (1.0f / D);
        float istd = rsqrtf(msq - mean * mean + 1e-5f);
        #pragma unroll
        for (int t = 0; t < 8; ++t) {
            int nn = t * 16 + c;
            float y2 = (y1[t][r] - mean) * istd * g2v[t] + b2v[t];
            float o = residual ? (gelu_exact(y2) + bf2f(h16_in[(size_t)n * D + nn])) : y2;
            if (n < N_NODES) {
                h16_out[(size_t)n * D + nn] = f2bf(o);
                if (write_f32) hf_out[(size_t)n * D + nn] = o;
            }
            if (DO_GATE) aggb[wave][m][nn] = f2bf(o);   // wave-private gate staging
        }
    }

    if (DO_GATE) {
        // gate MFMA: A from aggb[wave] (final h), B = wtg; K=128; all in-wave
        f32x4 gacc[8];
        #pragma unroll
        for (int t = 0; t < 8; ++t) {
            float bn = gb1[t * 16 + c];
            gacc[t] = (f32x4){bn, bn, bn, bn};
        }
        #pragma unroll
        for (int kk = 0; kk < 4; ++kk) {
            bf16x8 av = *(const bf16x8*)&aggb[wave][c][kk * 32 + q * 8];
            #pragma unroll
            for (int t = 0; t < 8; ++t) {
                bf16x8 bv = *(const bf16x8*)&wtg[(size_t)(t * 16 + c) * 128 + kk * 32 + q * 8];
                gacc[t] = __builtin_amdgcn_mfma_f32_16x16x32_bf16(av, bv, gacc[t], 0, 0, 0);
            }
        }
        float gs[4];
        #pragma unroll
        for (int r = 0; r < 4; ++r) {
            gs[r] = 0.f;
            #pragma unroll
            for (int t = 0; t < 8; ++t)
                gs[r] += tanhf(gacc[t][r]) * gw2[t * 16 + c];
        }
        #pragma unroll
        for (int o = 1; o <= 8; o <<= 1)
            #pragma unroll
            for (int r = 0; r < 4; ++r) gs[r] += __shfl_xor(gs[r], o);
        if (c == 0) {
            float bb2 = gb2[0];
            #pragma unroll
            for (int r = 0; r < 4; ++r) {
                int m = q * 4 + r;
                int n = nw0 + m;
                float L = gs[r] + bb2;
                if (n < N_NODES) { logits[n] = L; lg[wave * WNODE + m] = L; }
                else lg[wave * WNODE + m] = -INFINITY;
            }
        }
        __syncthreads();   // only barrier: cross-wave block softmax partial
        if (wave == 0) {
            float l = lg[lane];
            float mx = l;
            #pragma unroll
            for (int o = 32; o >= 1; o >>= 1) mx = fmaxf(mx, __shfl_xor(mx, o));
            float ex = (l > -INFINITY) ? expf(l - mx) : 0.f;
            #pragma unroll
            for (int o = 32; o >= 1; o >>= 1) ex += __shfl_xor(ex, o);
            if (lane == 0) gpart[blockIdx.x] = make_float2(mx, ex);
        }
    }
}

// ---------------- pool (stats folded in, 64-node chunks) / out ----------------

#define PC 64
__global__ __launch_bounds__(128) void gate_pool_v3(
        const unsigned short* __restrict__ h16, const float* __restrict__ logits,
        const float2* __restrict__ gpart, const int* __restrict__ batch,
        float* __restrict__ gate_out, float* __restrict__ pooled) {
    __shared__ float sb[4];
    __shared__ float gs[PC];
    __shared__ int bs[PC];
    int d = threadIdx.x;
    int lane = d & 63, wv = d >> 6;
    float mx = -INFINITY;
    for (int i = d; i < NBLK2; i += 128) mx = fmaxf(mx, gpart[i].x);
    #pragma unroll
    for (int o = 32; o >= 1; o >>= 1) mx = fmaxf(mx, __shfl_xor(mx, o));
    if (lane == 0) sb[wv] = mx;
    __syncthreads();
    mx = fmaxf(sb[0], sb[1]);
    float ssum = 0.f;
    for (int i = d; i < NBLK2; i += 128) {
        float2 p = gpart[i];
        ssum += p.y * expf(p.x - mx);
    }
    #pragma unroll
    for (int o = 32; o >= 1; o >>= 1) ssum += __shfl_xor(ssum, o);
    if (lane == 0) sb[2 + wv] = ssum;
    __syncthreads();
    float inv = 1.0f / (sb[2] + sb[3]);

    int n0 = blockIdx.x * PC;
    if (d < PC) {
        int nj = n0 + d;
        if (nj < N_NODES) {
            float gv = expf(logits[nj] - mx) * inv;
            gs[d] = gv;
            bs[d] = batch[nj];
            gate_out[nj] = gv;
        }
    }
    __syncthreads();
    int count = min(PC, N_NODES - n0);
    float acc = 0.f;
    int cur = bs[0];
    int t = 0;
    for (; t + 3 < count; t += 4) {
        float h0 = bf2f(h16[(size_t)(n0 + t + 0) * D + d]);
        float h1 = bf2f(h16[(size_t)(n0 + t + 1) * D + d]);
        float h2 = bf2f(h16[(size_t)(n0 + t + 2) * D + d]);
        float h3 = bf2f(h16[(size_t)(n0 + t + 3) * D + d]);
        int b0 = bs[t], b1 = bs[t + 1], b2 = bs[t + 2], b3 = bs[t + 3];
        if (b0 != cur) { atomicAdd(&pooled[cur * D + d], acc); acc = 0.f; cur = b0; }
        acc = fmaf(h0, gs[t], acc);
        if (b1 != cur) { atomicAdd(&pooled[cur * D + d], acc); acc = 0.f; cur = b1; }
        acc = fmaf(h1, gs[t + 1], acc);
        if (b2 != cur) { atomicAdd(&pooled[cur * D + d], acc); acc = 0.f; cur = b2; }
        acc = fmaf(h2, gs[t + 2], acc);
        if (b3 != cur) { atomicAdd(&pooled[cur * D + d], acc); acc = 0.f; cur = b3; }
        acc = fmaf(h3, gs[t + 3], acc);
    }
    for (; t < count; ++t) {
        int bn = bs[t];
        if (bn != cur) { atomicAdd(&pooled[cur * D + d], acc); acc = 0.f; cur = bn; }
        acc = fmaf(bf2f(h16[(size_t)(n0 + t) * D + d]), gs[t], acc);
    }
    atomicAdd(&pooled[cur * D + d], acc);
}

__global__ void out_proj_kernel(const float* __restrict__ pooled, const float* __restrict__ w,
                                const float* __restrict__ b, const float* __restrict__ g,
                                const float* __restrict__ beta, float* __restrict__ emb) {
    __shared__ float ps[D];
    __shared__ float sbuf[2];
    int bg = blockIdx.x, d = threadIdx.x;
    ps[d] = pooled[bg * D + d];
    __syncthreads();
    float acc = b[d];
    #pragma unroll 8
    for (int k = 0; k < D; ++k) acc += ps[k] * w[k * D + d];
    float s = acc, q = acc * acc;
    #pragma unroll
    for (int o = 32; o >= 1; o >>= 1) { s += __shfl_down(s, o); q += __shfl_down(q, o); }
    if ((d & 63) == 0) { sbuf[d >> 6] = s; }
    __syncthreads();
    float fullsum = sbuf[0] + sbuf[1];
    __syncthreads();
    if ((d & 63) == 0) { sbuf[d >> 6] = q; }
    __syncthreads();
    float fullsq = sbuf[0] + sbuf[1];
    float m = fullsum * (1.0f / D);
    float var = fullsq * (1.0f / D) - m * m;
    float y = (acc - m) * rsqrtf(var + 1e-5f) * g[d] + beta[d];
    emb[bg * D + d] = gelu_exact(y);
}

extern "C" void kernel_launch(void* const* d_in, const int* in_sizes, int n_in,
                              void* d_out, int out_size, void* d_ws, size_t ws_size,
                              hipStream_t stream) {
    const float* x        = (const float*)d_in[0];
    const int*   edge     = (const int*)d_in[1];
    const int*   batch    = (const int*)d_in[2];
    const float* w_in     = (const float*)d_in[3];
    const float* b_in     = (const float*)d_in[4];
    const float* ln_in_g  = (const float*)d_in[5];
    const float* ln_in_b  = (const float*)d_in[6];
    const float* gnn_w    = (const float*)d_in[7];
    const float* gnn_b    = (const float*)d_in[8];
    const float* gnn_ln_g = (const float*)d_in[9];
    const float* gnn_ln_b = (const float*)d_in[10];
    const float* norm_g   = (const float*)d_in[11];
    const float* norm_b   = (const float*)d_in[12];
    const float* gate_w1  = (const float*)d_in[13];
    const float* gate_b1  = (const float*)d_in[14];
    const float* gate_w2  = (const float*)d_in[15];
    const float* gate_b2  = (const float*)d_in[16];
    const float* out_w    = (const float*)d_in[17];
    const float* out_b    = (const float*)d_in[18];
    const float* out_ln_g = (const float*)d_in[19];
    const float* out_ln_b = (const float*)d_in[20];

    const int* src = edge;             // edge_index[0]
    const int* dst = edge + N_EDGES;   // edge_index[1]

    float* out      = (float*)d_out;
    float* emb      = out;                               // (8,128)
    float* hA       = out + B_GRAPHS * D;                // (N,128) final h (fp32)
    float* gate_out = hA + (size_t)N_NODES * D;          // (N,)

    unsigned short* h16A = (unsigned short*)d_ws;        // N*D bf16
    unsigned short* h16B = h16A + (size_t)N_NODES * D;   // N*D bf16
    int*   deg_i    = (int*)d_ws;                        // N      (overlay in h16A)
    int*   cursor   = (int*)d_ws + N_NODES;              // N+1    (overlay in h16A)
    int*   row_ptr  = (int*)(h16B + (size_t)N_NODES * D);// N+1
    int*   csr      = row_ptr + N_NODES + 1;             // E
    float* logits   = (float*)(csr + N_EDGES);           // N
    float* pooled   = logits + N_NODES;                  // 1024
    int*   partials = (int*)(pooled + B_GRAPHS * D);     // NPART
    float2* gpart   = (float2*)(((uintptr_t)(partials + NPART) + 15) & ~(uintptr_t)15); // NBLK2
    unsigned short* wt  = (unsigned short*)(gpart + NBLK2);
    unsigned short* wtg = wt + WT_GNN;
    unsigned short* wti = wt + WT_G1;

    // CSR build + W prep (+pooled zero)
    hipMemsetAsync(deg_i, 0, N_NODES * sizeof(int), stream);
    degree_kernel<<<(N_EDGES + 255) / 256, 256, 0, stream>>>(dst, deg_i);
    scan_partials_kernel<<<NPART, SCAN_B, 0, stream>>>(deg_i, partials);
    scan_apply_v2<<<NPART, SCAN_B, 0, stream>>>(deg_i, partials, row_ptr, cursor);
    fill_kernel<<<(N_EDGES + 255) / 256, 256, 0, stream>>>(src, dst, cursor, csr);
    wprep_kernel<<<(WT_ALL + 255) / 256, 256, 0, stream>>>(gnn_w, gate_w1, w_in, wt, pooled);

    // input proj (MFMA) -> h16B
    input_proj_v5<<<NBLK, 256, 0, stream>>>(x, wti, b_in, ln_in_g, ln_in_b, h16B);

    // layers: h16B -> h16A -> h16B -> (h16A + hA fp32 + gate fused)
    gnn_layer_v9<0><<<NBLK2, 256, 0, stream>>>(
        h16B, h16A, hA, csr, row_ptr, wt, gnn_b,
        gnn_ln_g, gnn_ln_b, norm_g, norm_b, 1, 0,
        nullptr, nullptr, nullptr, nullptr, nullptr, nullptr);
    gnn_layer_v9<0><<<NBLK2, 256, 0, stream>>>(
        h16A, h16B, hA, csr, row_ptr, wt + (size_t)1 * D * 2 * D, gnn_b + D,
        gnn_ln_g + D, gnn_ln_b + D, norm_g + D, norm_b + D, 1, 0,
        nullptr, nullptr, nullptr, nullptr, nullptr, nullptr);
    gnn_layer_v9<1><<<NBLK2, 256, 0, stream>>>(
        h16B, h16A, hA, csr, row_ptr, wt + (size_t)2 * D * 2 * D, gnn_b + 2 * D,
        gnn_ln_g + 2 * D, gnn_ln_b + 2 * D, norm_g + 2 * D, norm_b + 2 * D, 0, 1,
        wtg, gate_b1, gate_w2, gate_b2, logits, gpart);

    gate_pool_v3<<<(N_NODES + PC - 1) / PC, 128, 0, stream>>>(
        h16A, logits, gpart, batch, gate_out, pooled);
    out_proj_kernel<<<B_GRAPHS, D, 0, stream>>>(pooled, out_w, out_b, out_ln_g, out_ln_b, emb);
}